// Round 1
// baseline (13189.496 us; speedup 1.0000x reference)
//
#include <hip/hip_runtime.h>
#include <math.h>

#define NPTS    32768
#define NPOINT  2048
#define NSAMPLE 32
#define RADIUS2 0.25f
#define D_IN    64
#define D0      67
#define H1DIM   64
#define H2DIM   128

// ---------------------------------------------------------------------------
// Kernel A: farthest point sampling (single block, bit-exact vs numpy fp32)
// dist + x,y in registers (512 thr x 64 pts), z in LDS (128 KiB, swizzled).
// ---------------------------------------------------------------------------
#define FT 512
#define FK 64   // points per thread; FT*FK == NPTS

__global__ __launch_bounds__(FT) void fps_kernel(const float* __restrict__ xyz,
                                                 float* __restrict__ d_out)
{
#pragma clang fp contract(off)
    __shared__ float Zs[NPTS];
    __shared__ float red_v[FT / 64];
    __shared__ int   red_p[FT / 64];
    __shared__ float fb[3];

    const int t = threadIdx.x;
    const int base = t * FK;

    float X[FK], Y[FK], D[FK];

    #pragma unroll
    for (int j = 0; j < FK; ++j) {
        int p = base + j;
        X[j] = xyz[3 * p + 0];
        Y[j] = xyz[3 * p + 1];
        Zs[t * 64 + ((j + 4 * t) & 63)] = xyz[3 * p + 2];   // swizzle for b128 reads
        D[j] = 1e38f;
    }
    if (t == 0) { fb[0] = xyz[0]; fb[1] = xyz[1]; fb[2] = xyz[2]; }
    __syncthreads();

    for (int i = 0; i < NPOINT; ++i) {
        const float fx = fb[0], fy = fb[1], fz = fb[2];
        if (t == 0) {   // sel[i] = current far; emit its coords as new_xyz[i]
            d_out[3 * i + 0] = fx;
            d_out[3 * i + 1] = fy;
            d_out[3 * i + 2] = fz;
        }

        float bestd = -1.0f;
        int   bestp = 0;
        #pragma unroll
        for (int c = 0; c < FK / 4; ++c) {
            float4 z4 = *(const float4*)&Zs[t * 64 + ((4 * c + 4 * t) & 63)];
            float zz[4] = { z4.x, z4.y, z4.z, z4.w };
            #pragma unroll
            for (int r = 0; r < 4; ++r) {
                const int j = 4 * c + r;
                float dx = X[j] - fx;
                float dy = Y[j] - fy;
                float dz = zz[r] - fz;
                // exact np order: ((dx*dx + dy*dy) + dz*dz), no FMA contraction
                float d = ((dx * dx) + (dy * dy)) + (dz * dz);
                float Dn = fminf(D[j], d);
                D[j] = Dn;
                // strictly-greater keeps FIRST (lowest) index within thread
                if (Dn > bestd) { bestd = Dn; bestp = base + j; }
            }
        }

        // wave-level (val, first-index) argmax reduce
        #pragma unroll
        for (int mask = 32; mask >= 1; mask >>= 1) {
            float ov = __shfl_xor(bestd, mask, 64);
            int   op = __shfl_xor(bestp, mask, 64);
            if (ov > bestd || (ov == bestd && op < bestp)) { bestd = ov; bestp = op; }
        }
        if ((t & 63) == 0) { red_v[t >> 6] = bestd; red_p[t >> 6] = bestp; }
        __syncthreads();

        if (t < FT / 64) {   // 8 wave partials -> lanes 0..7 of wave 0
            bestd = red_v[t];
            bestp = red_p[t];
            #pragma unroll
            for (int mask = 4; mask >= 1; mask >>= 1) {
                float ov = __shfl_xor(bestd, mask, 8);
                int   op = __shfl_xor(bestp, mask, 8);
                if (ov > bestd || (ov == bestd && op < bestp)) { bestd = ov; bestp = op; }
            }
            if (t == 0) {
                fb[0] = xyz[3 * bestp + 0];
                fb[1] = xyz[3 * bestp + 1];
                fb[2] = xyz[3 * bestp + 2];
            }
        }
        __syncthreads();
    }
}

// ---------------------------------------------------------------------------
// Kernel B: ball query — exact (d2, idx)-lexicographic 32-smallest per centroid
// ---------------------------------------------------------------------------
#define BT   256
#define BCAP 3072   // in-radius cap (expected worst ~1100 near origin)

__global__ __launch_bounds__(BT) void ballq_kernel(const float* __restrict__ xyz,
                                                   const float* __restrict__ newxyz,
                                                   int* __restrict__ gidx)
{
#pragma clang fp contract(off)
    __shared__ float Ld[BCAP + 128];
    __shared__ int   Li[BCAP + 128];
    __shared__ int   cnt, pcnt;
    __shared__ float cs[3];
    __shared__ float rv[BT / 64];
    __shared__ int   ri[BT / 64], rj[BT / 64];

    const int m = blockIdx.x;
    const int t = threadIdx.x;

    if (t == 0) {
        cnt = 0; pcnt = 0;
        cs[0] = newxyz[3 * m + 0];
        cs[1] = newxyz[3 * m + 1];
        cs[2] = newxyz[3 * m + 2];
    }
    __syncthreads();
    const float cx = cs[0], cy = cs[1], cz = cs[2];

    for (int p = t; p < NPTS; p += BT) {
        float dx = cx - xyz[3 * p + 0];
        float dy = cy - xyz[3 * p + 1];
        float dz = cz - xyz[3 * p + 2];
        float d2 = ((dx * dx) + (dy * dy)) + (dz * dz);
        if (!(d2 > RADIUS2)) {                    // in radius (keeps d2 == r^2)
            int pos = atomicAdd(&cnt, 1);
            if (pos < BCAP) { Ld[pos] = d2; Li[pos] = p; }
        } else if (p < 128) {                     // padding candidates (masked 1e9)
            int pos = atomicAdd(&pcnt, 1);
            Ld[BCAP + pos] = 1e9f;
            Li[BCAP + pos] = p;
        }
    }
    __syncthreads();

    const int L = (cnt < BCAP) ? cnt : BCAP;
    const int P = pcnt;
    if (t < P) {  // compact pads to follow the in-radius list
        float d = Ld[BCAP + t];
        int   x = Li[BCAP + t];
        Ld[L + t] = d;
        Li[L + t] = x;
    }
    __syncthreads();
    const int M = L + P;

    for (int r = 0; r < NSAMPLE; ++r) {
        float bd = 3e38f;
        int   bi = 0x7fffffff;
        int   bj = 0;
        for (int j = t; j < M; j += BT) {
            float d = Ld[j];
            int   x = Li[j];
            if (d < bd || (d == bd && x < bi)) { bd = d; bi = x; bj = j; }
        }
        #pragma unroll
        for (int mask = 32; mask >= 1; mask >>= 1) {
            float ov = __shfl_xor(bd, mask, 64);
            int   oi = __shfl_xor(bi, mask, 64);
            int   oj = __shfl_xor(bj, mask, 64);
            if (ov < bd || (ov == bd && oi < bi)) { bd = ov; bi = oi; bj = oj; }
        }
        if ((t & 63) == 0) { rv[t >> 6] = bd; ri[t >> 6] = bi; rj[t >> 6] = bj; }
        __syncthreads();
        if (t == 0) {
            float v0 = rv[0]; int i0 = ri[0]; int j0 = rj[0];
            for (int w = 1; w < BT / 64; ++w) {
                if (rv[w] < v0 || (rv[w] == v0 && ri[w] < i0)) { v0 = rv[w]; i0 = ri[w]; j0 = rj[w]; }
            }
            gidx[m * NSAMPLE + r] = i0;
            Ld[j0] = 3e38f;   // remove from candidate set
        }
        __syncthreads();
    }
}

// ---------------------------------------------------------------------------
// Kernel C: gather -> MLP(67->64->128, exact GELU) -> maxpool, 1 block/centroid
// ---------------------------------------------------------------------------
__global__ __launch_bounds__(256) void mlp_kernel(const float* __restrict__ xyz,
                                                  const float* __restrict__ feat,
                                                  const float* __restrict__ W1,
                                                  const float* __restrict__ b1,
                                                  const float* __restrict__ W2,
                                                  const float* __restrict__ b2,
                                                  const float* __restrict__ newxyz,
                                                  const int* __restrict__ gidx,
                                                  float* __restrict__ out_pooled)
{
    __shared__ float W1s[D0 * H1DIM];            // 17152 B
    __shared__ float W2s[H1DIM * H2DIM];         // 32768 B
    __shared__ float b1s[H1DIM];
    __shared__ float b2s[H2DIM];
    __shared__ float Xs[NSAMPLE][D0 + 1];        // 68 stride
    __shared__ float H1s[NSAMPLE][H1DIM + 4];    // 68 stride
    __shared__ float H2s[NSAMPLE][H2DIM + 4];    // 132 stride
    __shared__ int   idxs[NSAMPLE];
    __shared__ float cs[3];

    const int m = blockIdx.x;
    const int t = threadIdx.x;

    for (int i = t; i < D0 * H1DIM; i += 256) W1s[i] = W1[i];
    for (int i = t; i < H1DIM * H2DIM; i += 256) W2s[i] = W2[i];
    if (t < H1DIM) b1s[t] = b1[t];
    if (t < H2DIM) b2s[t] = b2[t];
    if (t < NSAMPLE) idxs[t] = gidx[m * NSAMPLE + t];
    if (t < 3) cs[t] = newxyz[3 * m + t];
    __syncthreads();

    const int s  = t >> 3;   // sample 0..31
    const int u  = t & 7;    // sub-worker 0..7

    {   // gather: g_xyz (relative) + feat
        const int id = idxs[s];
        const float4* f4 = (const float4*)(feat + (size_t)id * D_IN);
        float4 a = f4[u * 2 + 0];
        float4 b = f4[u * 2 + 1];
        Xs[s][3 + u * 8 + 0] = a.x; Xs[s][3 + u * 8 + 1] = a.y;
        Xs[s][3 + u * 8 + 2] = a.z; Xs[s][3 + u * 8 + 3] = a.w;
        Xs[s][3 + u * 8 + 4] = b.x; Xs[s][3 + u * 8 + 5] = b.y;
        Xs[s][3 + u * 8 + 6] = b.z; Xs[s][3 + u * 8 + 7] = b.w;
        if (u == 0) {
            Xs[s][0] = xyz[3 * id + 0] - cs[0];
            Xs[s][1] = xyz[3 * id + 1] - cs[1];
            Xs[s][2] = xyz[3 * id + 2] - cs[2];
        }
    }
    __syncthreads();

    // layer 1: each thread computes 8 of 64 outputs for its sample
    {
        float acc[8];
        #pragma unroll
        for (int v = 0; v < 8; ++v) acc[v] = b1s[u * 8 + v];
        for (int k = 0; k < D0; ++k) {
            float xk = Xs[s][k];
            float4 wa = *(const float4*)&W1s[k * H1DIM + u * 8 + 0];
            float4 wb = *(const float4*)&W1s[k * H1DIM + u * 8 + 4];
            acc[0] = fmaf(xk, wa.x, acc[0]); acc[1] = fmaf(xk, wa.y, acc[1]);
            acc[2] = fmaf(xk, wa.z, acc[2]); acc[3] = fmaf(xk, wa.w, acc[3]);
            acc[4] = fmaf(xk, wb.x, acc[4]); acc[5] = fmaf(xk, wb.y, acc[5]);
            acc[6] = fmaf(xk, wb.z, acc[6]); acc[7] = fmaf(xk, wb.w, acc[7]);
        }
        #pragma unroll
        for (int v = 0; v < 8; ++v) {
            float a = acc[v];
            H1s[s][u * 8 + v] = 0.5f * a * (1.0f + erff(a * 0.70710678118654752f));
        }
    }
    __syncthreads();

    // layer 2: each thread computes 16 of 128 outputs for its sample
    {
        float acc[16];
        #pragma unroll
        for (int v = 0; v < 16; ++v) acc[v] = b2s[u * 16 + v];
        for (int k = 0; k < H1DIM; ++k) {
            float hk = H1s[s][k];
            #pragma unroll
            for (int q = 0; q < 4; ++q) {
                float4 w = *(const float4*)&W2s[k * H2DIM + u * 16 + q * 4];
                acc[q * 4 + 0] = fmaf(hk, w.x, acc[q * 4 + 0]);
                acc[q * 4 + 1] = fmaf(hk, w.y, acc[q * 4 + 1]);
                acc[q * 4 + 2] = fmaf(hk, w.z, acc[q * 4 + 2]);
                acc[q * 4 + 3] = fmaf(hk, w.w, acc[q * 4 + 3]);
            }
        }
        #pragma unroll
        for (int v = 0; v < 16; ++v) {
            float a = acc[v];
            H2s[s][u * 16 + v] = 0.5f * a * (1.0f + erff(a * 0.70710678118654752f));
        }
    }
    __syncthreads();

    // maxpool over 32 samples
    if (t < H2DIM) {
        float mx = H2s[0][t];
        #pragma unroll 4
        for (int ss = 1; ss < NSAMPLE; ++ss) mx = fmaxf(mx, H2s[ss][t]);
        out_pooled[(size_t)m * H2DIM + t] = mx;
    }
}

// ---------------------------------------------------------------------------
extern "C" void kernel_launch(void* const* d_in, const int* in_sizes, int n_in,
                              void* d_out, int out_size, void* d_ws, size_t ws_size,
                              hipStream_t stream) {
    const float* xyz  = (const float*)d_in[0];
    const float* feat = (const float*)d_in[1];
    const float* W1   = (const float*)d_in[2];
    const float* b1   = (const float*)d_in[3];
    const float* W2   = (const float*)d_in[4];
    const float* b2   = (const float*)d_in[5];
    float* out = (float*)d_out;
    int*   gidx = (int*)d_ws;   // 2048*32 ints = 256 KiB scratch

    fps_kernel<<<1, FT, 0, stream>>>(xyz, out);
    ballq_kernel<<<NPOINT, BT, 0, stream>>>(xyz, out, gidx);
    mlp_kernel<<<NPOINT, 256, 0, stream>>>(xyz, feat, W1, b1, W2, b2,
                                           out, gidx, out + 3 * NPOINT);
}

// Round 2
// 12477.737 us; speedup vs baseline: 1.0570x; 1.0570x over previous
//
#include <hip/hip_runtime.h>
#include <math.h>

#define NPTS    32768
#define NPOINT  2048
#define NSAMPLE 32
#define RADIUS2 0.25f
#define D_IN    64
#define D0      67
#define H1DIM   64
#define H2DIM   128

// ---------------------------------------------------------------------------
// Kernel A: farthest point sampling (single block, bit-exact vs numpy fp32)
// 1024 thr x 32 pts: X,Y,D in registers (96 VGPR, no spill), z in LDS.
// Deferred argmax: per-point cost is min+max only; index recovered by
// equality scan on the (rare) winning thread(s) via atomicMin.
// ---------------------------------------------------------------------------
#define FT 1024
#define FK 32   // points per thread; FT*FK == NPTS

__global__ __launch_bounds__(FT) void fps_kernel(const float* __restrict__ xyz,
                                                 float* __restrict__ d_out)
{
#pragma clang fp contract(off)
    __shared__ float Zs[NPTS];          // 128 KiB
    __shared__ float red_v[FT / 64];    // 16 wave partials
    __shared__ int   widx_s;

    const int t = threadIdx.x;
    const int base = t * FK;

    float X[FK], Y[FK], D[FK];

    #pragma unroll
    for (int j = 0; j < FK; ++j) {
        int p = base + j;
        X[j] = xyz[3 * p + 0];
        Y[j] = xyz[3 * p + 1];
        Zs[t * FK + ((j + 4 * t) & (FK - 1))] = xyz[3 * p + 2];  // swizzled row
        D[j] = 1e38f;
    }
    if (t == 0) widx_s = 0x7fffffff;
    float fx = xyz[0], fy = xyz[1], fz = xyz[2];   // far = 0 at start
    __syncthreads();

    for (int i = 0; i < NPOINT; ++i) {
        if (t == 0) {   // emit current far point's coords as new_xyz[i]
            d_out[3 * i + 0] = fx;
            d_out[3 * i + 1] = fy;
            d_out[3 * i + 2] = fz;
        }

        // --- distance update + max (4 independent accumulators for ILP) ---
        float m0 = -1.0f, m1 = -1.0f, m2 = -1.0f, m3 = -1.0f;
        #pragma unroll
        for (int c = 0; c < FK / 4; ++c) {
            float4 z4 = *(const float4*)&Zs[t * FK + ((4 * c + 4 * t) & (FK - 1))];
            {   const int j = 4 * c + 0;
                float dx = X[j] - fx, dy = Y[j] - fy, dz = z4.x - fz;
                float d = ((dx * dx) + (dy * dy)) + (dz * dz);
                float Dn = fminf(D[j], d); D[j] = Dn; m0 = fmaxf(m0, Dn); }
            {   const int j = 4 * c + 1;
                float dx = X[j] - fx, dy = Y[j] - fy, dz = z4.y - fz;
                float d = ((dx * dx) + (dy * dy)) + (dz * dz);
                float Dn = fminf(D[j], d); D[j] = Dn; m1 = fmaxf(m1, Dn); }
            {   const int j = 4 * c + 2;
                float dx = X[j] - fx, dy = Y[j] - fy, dz = z4.z - fz;
                float d = ((dx * dx) + (dy * dy)) + (dz * dz);
                float Dn = fminf(D[j], d); D[j] = Dn; m2 = fmaxf(m2, Dn); }
            {   const int j = 4 * c + 3;
                float dx = X[j] - fx, dy = Y[j] - fy, dz = z4.w - fz;
                float d = ((dx * dx) + (dy * dy)) + (dz * dz);
                float Dn = fminf(D[j], d); D[j] = Dn; m3 = fmaxf(m3, Dn); }
        }
        const float tmax = fmaxf(fmaxf(m0, m1), fmaxf(m2, m3));  // thread max

        // --- wave max ---
        float wmax = tmax;
        #pragma unroll
        for (int mask = 32; mask >= 1; mask >>= 1)
            wmax = fmaxf(wmax, __shfl_xor(wmax, mask, 64));
        if ((t & 63) == 0) red_v[t >> 6] = wmax;
        __syncthreads();                                   // A

        // --- every wave redundantly reduces the 16 partials -> gmax ---
        float pv = red_v[t & 15];
        #pragma unroll
        for (int mask = 8; mask >= 1; mask >>= 1)
            pv = fmaxf(pv, __shfl_xor(pv, mask, 16));
        const float gmax = pv;

        // --- winning thread(s) recover first (lowest) index by equality ---
        if (tmax == gmax) {
            int loc = -1;
            #pragma unroll
            for (int j = FK - 1; j >= 0; --j)
                if (D[j] == gmax) loc = j;    // downward scan -> lowest j wins
            if (loc >= 0) atomicMin(&widx_s, base + loc);
        }
        __syncthreads();                                   // C

        const int w = __builtin_amdgcn_readfirstlane(widx_s);
        fx = xyz[3 * w + 0];   // uniform address -> L1 broadcast
        fy = xyz[3 * w + 1];
        fz = xyz[3 * w + 2];
        __syncthreads();                                   // D
        if (t == 0) widx_s = 0x7fffffff;
        // reset is after D (readers done) and before next A (next atomicMin)
    }
}

// ---------------------------------------------------------------------------
// Kernel B: ball query — exact (d2, idx)-lexicographic 32-smallest per centroid
// ---------------------------------------------------------------------------
#define BT   256
#define BCAP 3072   // in-radius cap (expected worst ~1100 near origin)

__global__ __launch_bounds__(BT) void ballq_kernel(const float* __restrict__ xyz,
                                                   const float* __restrict__ newxyz,
                                                   int* __restrict__ gidx)
{
#pragma clang fp contract(off)
    __shared__ float Ld[BCAP + 128];
    __shared__ int   Li[BCAP + 128];
    __shared__ int   cnt, pcnt;
    __shared__ float cs[3];
    __shared__ float rv[BT / 64];
    __shared__ int   ri[BT / 64], rj[BT / 64];

    const int m = blockIdx.x;
    const int t = threadIdx.x;

    if (t == 0) {
        cnt = 0; pcnt = 0;
        cs[0] = newxyz[3 * m + 0];
        cs[1] = newxyz[3 * m + 1];
        cs[2] = newxyz[3 * m + 2];
    }
    __syncthreads();
    const float cx = cs[0], cy = cs[1], cz = cs[2];

    for (int p = t; p < NPTS; p += BT) {
        float dx = cx - xyz[3 * p + 0];
        float dy = cy - xyz[3 * p + 1];
        float dz = cz - xyz[3 * p + 2];
        float d2 = ((dx * dx) + (dy * dy)) + (dz * dz);
        if (!(d2 > RADIUS2)) {                    // in radius (keeps d2 == r^2)
            int pos = atomicAdd(&cnt, 1);
            if (pos < BCAP) { Ld[pos] = d2; Li[pos] = p; }
        } else if (p < 128) {                     // padding candidates (masked 1e9)
            int pos = atomicAdd(&pcnt, 1);
            Ld[BCAP + pos] = 1e9f;
            Li[BCAP + pos] = p;
        }
    }
    __syncthreads();

    const int L = (cnt < BCAP) ? cnt : BCAP;
    const int P = pcnt;
    if (t < P) {  // compact pads to follow the in-radius list
        float d = Ld[BCAP + t];
        int   x = Li[BCAP + t];
        Ld[L + t] = d;
        Li[L + t] = x;
    }
    __syncthreads();
    const int M = L + P;

    for (int r = 0; r < NSAMPLE; ++r) {
        float bd = 3e38f;
        int   bi = 0x7fffffff;
        int   bj = 0;
        for (int j = t; j < M; j += BT) {
            float d = Ld[j];
            int   x = Li[j];
            if (d < bd || (d == bd && x < bi)) { bd = d; bi = x; bj = j; }
        }
        #pragma unroll
        for (int mask = 32; mask >= 1; mask >>= 1) {
            float ov = __shfl_xor(bd, mask, 64);
            int   oi = __shfl_xor(bi, mask, 64);
            int   oj = __shfl_xor(bj, mask, 64);
            if (ov < bd || (ov == bd && oi < bi)) { bd = ov; bi = oi; bj = oj; }
        }
        if ((t & 63) == 0) { rv[t >> 6] = bd; ri[t >> 6] = bi; rj[t >> 6] = bj; }
        __syncthreads();
        if (t == 0) {
            float v0 = rv[0]; int i0 = ri[0]; int j0 = rj[0];
            for (int w = 1; w < BT / 64; ++w) {
                if (rv[w] < v0 || (rv[w] == v0 && ri[w] < i0)) { v0 = rv[w]; i0 = ri[w]; j0 = rj[w]; }
            }
            gidx[m * NSAMPLE + r] = i0;
            Ld[j0] = 3e38f;   // remove from candidate set
        }
        __syncthreads();
    }
}

// ---------------------------------------------------------------------------
// Kernel C: gather -> MLP(67->64->128, exact GELU) -> maxpool, 1 block/centroid
// ---------------------------------------------------------------------------
__global__ __launch_bounds__(256) void mlp_kernel(const float* __restrict__ xyz,
                                                  const float* __restrict__ feat,
                                                  const float* __restrict__ W1,
                                                  const float* __restrict__ b1,
                                                  const float* __restrict__ W2,
                                                  const float* __restrict__ b2,
                                                  const float* __restrict__ newxyz,
                                                  const int* __restrict__ gidx,
                                                  float* __restrict__ out_pooled)
{
    __shared__ float W1s[D0 * H1DIM];            // 17152 B
    __shared__ float W2s[H1DIM * H2DIM];         // 32768 B
    __shared__ float b1s[H1DIM];
    __shared__ float b2s[H2DIM];
    __shared__ float Xs[NSAMPLE][D0 + 1];        // 68 stride
    __shared__ float H1s[NSAMPLE][H1DIM + 4];    // 68 stride
    __shared__ float H2s[NSAMPLE][H2DIM + 4];    // 132 stride
    __shared__ int   idxs[NSAMPLE];
    __shared__ float cs[3];

    const int m = blockIdx.x;
    const int t = threadIdx.x;

    for (int i = t; i < D0 * H1DIM; i += 256) W1s[i] = W1[i];
    for (int i = t; i < H1DIM * H2DIM; i += 256) W2s[i] = W2[i];
    if (t < H1DIM) b1s[t] = b1[t];
    if (t < H2DIM) b2s[t] = b2[t];
    if (t < NSAMPLE) idxs[t] = gidx[m * NSAMPLE + t];
    if (t < 3) cs[t] = newxyz[3 * m + t];
    __syncthreads();

    const int s  = t >> 3;   // sample 0..31
    const int u  = t & 7;    // sub-worker 0..7

    {   // gather: g_xyz (relative) + feat
        const int id = idxs[s];
        const float4* f4 = (const float4*)(feat + (size_t)id * D_IN);
        float4 a = f4[u * 2 + 0];
        float4 b = f4[u * 2 + 1];
        Xs[s][3 + u * 8 + 0] = a.x; Xs[s][3 + u * 8 + 1] = a.y;
        Xs[s][3 + u * 8 + 2] = a.z; Xs[s][3 + u * 8 + 3] = a.w;
        Xs[s][3 + u * 8 + 4] = b.x; Xs[s][3 + u * 8 + 5] = b.y;
        Xs[s][3 + u * 8 + 6] = b.z; Xs[s][3 + u * 8 + 7] = b.w;
        if (u == 0) {
            Xs[s][0] = xyz[3 * id + 0] - cs[0];
            Xs[s][1] = xyz[3 * id + 1] - cs[1];
            Xs[s][2] = xyz[3 * id + 2] - cs[2];
        }
    }
    __syncthreads();

    // layer 1: each thread computes 8 of 64 outputs for its sample
    {
        float acc[8];
        #pragma unroll
        for (int v = 0; v < 8; ++v) acc[v] = b1s[u * 8 + v];
        for (int k = 0; k < D0; ++k) {
            float xk = Xs[s][k];
            float4 wa = *(const float4*)&W1s[k * H1DIM + u * 8 + 0];
            float4 wb = *(const float4*)&W1s[k * H1DIM + u * 8 + 4];
            acc[0] = fmaf(xk, wa.x, acc[0]); acc[1] = fmaf(xk, wa.y, acc[1]);
            acc[2] = fmaf(xk, wa.z, acc[2]); acc[3] = fmaf(xk, wa.w, acc[3]);
            acc[4] = fmaf(xk, wb.x, acc[4]); acc[5] = fmaf(xk, wb.y, acc[5]);
            acc[6] = fmaf(xk, wb.z, acc[6]); acc[7] = fmaf(xk, wb.w, acc[7]);
        }
        #pragma unroll
        for (int v = 0; v < 8; ++v) {
            float a = acc[v];
            H1s[s][u * 8 + v] = 0.5f * a * (1.0f + erff(a * 0.70710678118654752f));
        }
    }
    __syncthreads();

    // layer 2: each thread computes 16 of 128 outputs for its sample
    {
        float acc[16];
        #pragma unroll
        for (int v = 0; v < 16; ++v) acc[v] = b2s[u * 16 + v];
        for (int k = 0; k < H1DIM; ++k) {
            float hk = H1s[s][k];
            #pragma unroll
            for (int q = 0; q < 4; ++q) {
                float4 w = *(const float4*)&W2s[k * H2DIM + u * 16 + q * 4];
                acc[q * 4 + 0] = fmaf(hk, w.x, acc[q * 4 + 0]);
                acc[q * 4 + 1] = fmaf(hk, w.y, acc[q * 4 + 1]);
                acc[q * 4 + 2] = fmaf(hk, w.z, acc[q * 4 + 2]);
                acc[q * 4 + 3] = fmaf(hk, w.w, acc[q * 4 + 3]);
            }
        }
        #pragma unroll
        for (int v = 0; v < 16; ++v) {
            float a = acc[v];
            H2s[s][u * 16 + v] = 0.5f * a * (1.0f + erff(a * 0.70710678118654752f));
        }
    }
    __syncthreads();

    // maxpool over 32 samples
    if (t < H2DIM) {
        float mx = H2s[0][t];
        #pragma unroll 4
        for (int ss = 1; ss < NSAMPLE; ++ss) mx = fmaxf(mx, H2s[ss][t]);
        out_pooled[(size_t)m * H2DIM + t] = mx;
    }
}

// ---------------------------------------------------------------------------
extern "C" void kernel_launch(void* const* d_in, const int* in_sizes, int n_in,
                              void* d_out, int out_size, void* d_ws, size_t ws_size,
                              hipStream_t stream) {
    const float* xyz  = (const float*)d_in[0];
    const float* feat = (const float*)d_in[1];
    const float* W1   = (const float*)d_in[2];
    const float* b1   = (const float*)d_in[3];
    const float* W2   = (const float*)d_in[4];
    const float* b2   = (const float*)d_in[5];
    float* out = (float*)d_out;
    int*   gidx = (int*)d_ws;   // 2048*32 ints = 256 KiB scratch

    fps_kernel<<<1, FT, 0, stream>>>(xyz, out);
    ballq_kernel<<<NPOINT, BT, 0, stream>>>(xyz, out, gidx);
    mlp_kernel<<<NPOINT, 256, 0, stream>>>(xyz, feat, W1, b1, W2, b2,
                                           out, gidx, out + 3 * NPOINT);
}

// Round 3
// 6081.782 us; speedup vs baseline: 2.1687x; 2.0517x over previous
//
#include <hip/hip_runtime.h>
#include <math.h>

#define NPTS    32768
#define NPOINT  2048
#define NSAMPLE 32
#define RADIUS2 0.25f
#define D_IN    64
#define D0      67
#define H1DIM   64
#define H2DIM   128

// ---------------------------------------------------------------------------
// Kernel A: farthest point sampling (single block, bit-exact vs numpy fp32)
// 512 thr x 64 pts. __launch_bounds__(512,2) -> 256-VGPR cap: X,Y,D (192) in
// registers with ~45 regs headroom, z in LDS (128 KiB) laid out so each wave
// ds_read_b128 is lane-consecutive (conflict-free). Deferred argmax: per-point
// cost is min+max; winning index recovered by equality scan + LDS atomicMin.
// Point ownership: thread t owns p = g*2048 + 4t + k (g=0..15, k=0..3).
// ---------------------------------------------------------------------------
#define FT 512
#define FK 64   // points per thread; FT*FK == NPTS

__global__ __launch_bounds__(FT, 2) void fps_kernel(const float* __restrict__ xyz,
                                                    float* __restrict__ d_out)
{
#pragma clang fp contract(off)
    __shared__ float Zs[NPTS];          // 128 KiB, Zs[p] = z of point p
    __shared__ float red_v[FT / 64];    // 8 wave partials
    __shared__ int   widx_s[2];         // ping-pong argmax index slot

    const int t = threadIdx.x;

    float X[FK], Y[FK], D[FK];

    #pragma unroll
    for (int g = 0; g < 16; ++g)
        #pragma unroll
        for (int k = 0; k < 4; ++k) {
            const int j = g * 4 + k;
            const int p = g * 2048 + t * 4 + k;
            X[j] = xyz[3 * p + 0];
            Y[j] = xyz[3 * p + 1];
            Zs[p] = xyz[3 * p + 2];
            D[j] = 1e38f;
        }
    if (t == 0) { widx_s[0] = 0x7fffffff; widx_s[1] = 0x7fffffff; }
    float fx = xyz[0], fy = xyz[1], fz = xyz[2];   // far = 0 at start
    __syncthreads();

    for (int i = 0; i < NPOINT; ++i) {
        const int par = i & 1;
        if (t == 0) {   // emit current far point's coords as new_xyz[i]
            d_out[3 * i + 0] = fx;
            d_out[3 * i + 1] = fy;
            d_out[3 * i + 2] = fz;
        }

        // --- distance update + max (4 independent accumulators for ILP) ---
        float m0 = -1.0f, m1 = -1.0f, m2 = -1.0f, m3 = -1.0f;
        #pragma unroll
        for (int g = 0; g < 16; ++g) {
            float4 z4 = *(const float4*)&Zs[g * 2048 + t * 4];  // lane-consecutive
            {   const int j = g * 4 + 0;
                float dx = X[j] - fx, dy = Y[j] - fy, dz = z4.x - fz;
                float d = ((dx * dx) + (dy * dy)) + (dz * dz);
                float Dn = fminf(D[j], d); D[j] = Dn; m0 = fmaxf(m0, Dn); }
            {   const int j = g * 4 + 1;
                float dx = X[j] - fx, dy = Y[j] - fy, dz = z4.y - fz;
                float d = ((dx * dx) + (dy * dy)) + (dz * dz);
                float Dn = fminf(D[j], d); D[j] = Dn; m1 = fmaxf(m1, Dn); }
            {   const int j = g * 4 + 2;
                float dx = X[j] - fx, dy = Y[j] - fy, dz = z4.z - fz;
                float d = ((dx * dx) + (dy * dy)) + (dz * dz);
                float Dn = fminf(D[j], d); D[j] = Dn; m2 = fmaxf(m2, Dn); }
            {   const int j = g * 4 + 3;
                float dx = X[j] - fx, dy = Y[j] - fy, dz = z4.w - fz;
                float d = ((dx * dx) + (dy * dy)) + (dz * dz);
                float Dn = fminf(D[j], d); D[j] = Dn; m3 = fmaxf(m3, Dn); }
        }
        const float tmax = fmaxf(fmaxf(m0, m1), fmaxf(m2, m3));  // thread max

        // --- wave max ---
        float wmax = tmax;
        #pragma unroll
        for (int mask = 32; mask >= 1; mask >>= 1)
            wmax = fmaxf(wmax, __shfl_xor(wmax, mask, 64));
        if ((t & 63) == 0) red_v[t >> 6] = wmax;
        __syncthreads();                                   // A

        // --- every wave redundantly reduces the 8 partials -> gmax ---
        float pv = red_v[t & 7];
        #pragma unroll
        for (int mask = 4; mask >= 1; mask >>= 1)
            pv = fmaxf(pv, __shfl_xor(pv, mask, 8));
        const float gmax = pv;

        // --- winning thread(s) recover first (lowest) index by equality ---
        if (tmax == gmax) {
            int loc = -1;
            #pragma unroll
            for (int j = FK - 1; j >= 0; --j)
                if (D[j] == gmax) loc = j;    // downward scan -> lowest j wins
            if (loc >= 0)
                atomicMin(&widx_s[par], (loc >> 2) * 2048 + t * 4 + (loc & 3));
        }
        __syncthreads();                                   // C

        const int w = __builtin_amdgcn_readfirstlane(widx_s[par]);
        if (t == 0) widx_s[par ^ 1] = 0x7fffffff;
        // slot par^1: last read was before barrier A (iter i-1 epoch);
        // next atomicMin is after barrier A of iter i+1 -> race-free.
        fx = xyz[3 * w + 0];   // uniform address -> scalar load broadcast
        fy = xyz[3 * w + 1];
        fz = xyz[3 * w + 2];
    }
}

// ---------------------------------------------------------------------------
// Kernel B: ball query — exact (d2, idx)-lexicographic 32-smallest per centroid
// ---------------------------------------------------------------------------
#define BT   256
#define BCAP 3072   // in-radius cap (expected worst ~1100 near origin)

__global__ __launch_bounds__(BT) void ballq_kernel(const float* __restrict__ xyz,
                                                   const float* __restrict__ newxyz,
                                                   int* __restrict__ gidx)
{
#pragma clang fp contract(off)
    __shared__ float Ld[BCAP + 128];
    __shared__ int   Li[BCAP + 128];
    __shared__ int   cnt, pcnt;
    __shared__ float cs[3];
    __shared__ float rv[BT / 64];
    __shared__ int   ri[BT / 64], rj[BT / 64];

    const int m = blockIdx.x;
    const int t = threadIdx.x;

    if (t == 0) {
        cnt = 0; pcnt = 0;
        cs[0] = newxyz[3 * m + 0];
        cs[1] = newxyz[3 * m + 1];
        cs[2] = newxyz[3 * m + 2];
    }
    __syncthreads();
    const float cx = cs[0], cy = cs[1], cz = cs[2];

    for (int p = t; p < NPTS; p += BT) {
        float dx = cx - xyz[3 * p + 0];
        float dy = cy - xyz[3 * p + 1];
        float dz = cz - xyz[3 * p + 2];
        float d2 = ((dx * dx) + (dy * dy)) + (dz * dz);
        if (!(d2 > RADIUS2)) {                    // in radius (keeps d2 == r^2)
            int pos = atomicAdd(&cnt, 1);
            if (pos < BCAP) { Ld[pos] = d2; Li[pos] = p; }
        } else if (p < 128) {                     // padding candidates (masked 1e9)
            int pos = atomicAdd(&pcnt, 1);
            Ld[BCAP + pos] = 1e9f;
            Li[BCAP + pos] = p;
        }
    }
    __syncthreads();

    const int L = (cnt < BCAP) ? cnt : BCAP;
    const int P = pcnt;
    if (t < P) {  // compact pads to follow the in-radius list
        float d = Ld[BCAP + t];
        int   x = Li[BCAP + t];
        Ld[L + t] = d;
        Li[L + t] = x;
    }
    __syncthreads();
    const int M = L + P;

    for (int r = 0; r < NSAMPLE; ++r) {
        float bd = 3e38f;
        int   bi = 0x7fffffff;
        int   bj = 0;
        for (int j = t; j < M; j += BT) {
            float d = Ld[j];
            int   x = Li[j];
            if (d < bd || (d == bd && x < bi)) { bd = d; bi = x; bj = j; }
        }
        #pragma unroll
        for (int mask = 32; mask >= 1; mask >>= 1) {
            float ov = __shfl_xor(bd, mask, 64);
            int   oi = __shfl_xor(bi, mask, 64);
            int   oj = __shfl_xor(bj, mask, 64);
            if (ov < bd || (ov == bd && oi < bi)) { bd = ov; bi = oi; bj = oj; }
        }
        if ((t & 63) == 0) { rv[t >> 6] = bd; ri[t >> 6] = bi; rj[t >> 6] = bj; }
        __syncthreads();
        if (t == 0) {
            float v0 = rv[0]; int i0 = ri[0]; int j0 = rj[0];
            for (int w = 1; w < BT / 64; ++w) {
                if (rv[w] < v0 || (rv[w] == v0 && ri[w] < i0)) { v0 = rv[w]; i0 = ri[w]; j0 = rj[w]; }
            }
            gidx[m * NSAMPLE + r] = i0;
            Ld[j0] = 3e38f;   // remove from candidate set
        }
        __syncthreads();
    }
}

// ---------------------------------------------------------------------------
// Kernel C: gather -> MLP(67->64->128, exact GELU) -> maxpool, 1 block/centroid
// ---------------------------------------------------------------------------
__global__ __launch_bounds__(256) void mlp_kernel(const float* __restrict__ xyz,
                                                  const float* __restrict__ feat,
                                                  const float* __restrict__ W1,
                                                  const float* __restrict__ b1,
                                                  const float* __restrict__ W2,
                                                  const float* __restrict__ b2,
                                                  const float* __restrict__ newxyz,
                                                  const int* __restrict__ gidx,
                                                  float* __restrict__ out_pooled)
{
    __shared__ float W1s[D0 * H1DIM];            // 17152 B
    __shared__ float W2s[H1DIM * H2DIM];         // 32768 B
    __shared__ float b1s[H1DIM];
    __shared__ float b2s[H2DIM];
    __shared__ float Xs[NSAMPLE][D0 + 1];        // 68 stride
    __shared__ float H1s[NSAMPLE][H1DIM + 4];    // 68 stride
    __shared__ float H2s[NSAMPLE][H2DIM + 4];    // 132 stride
    __shared__ int   idxs[NSAMPLE];
    __shared__ float cs[3];

    const int m = blockIdx.x;
    const int t = threadIdx.x;

    for (int i = t; i < D0 * H1DIM; i += 256) W1s[i] = W1[i];
    for (int i = t; i < H1DIM * H2DIM; i += 256) W2s[i] = W2[i];
    if (t < H1DIM) b1s[t] = b1[t];
    if (t < H2DIM) b2s[t] = b2[t];
    if (t < NSAMPLE) idxs[t] = gidx[m * NSAMPLE + t];
    if (t < 3) cs[t] = newxyz[3 * m + t];
    __syncthreads();

    const int s  = t >> 3;   // sample 0..31
    const int u  = t & 7;    // sub-worker 0..7

    {   // gather: g_xyz (relative) + feat
        const int id = idxs[s];
        const float4* f4 = (const float4*)(feat + (size_t)id * D_IN);
        float4 a = f4[u * 2 + 0];
        float4 b = f4[u * 2 + 1];
        Xs[s][3 + u * 8 + 0] = a.x; Xs[s][3 + u * 8 + 1] = a.y;
        Xs[s][3 + u * 8 + 2] = a.z; Xs[s][3 + u * 8 + 3] = a.w;
        Xs[s][3 + u * 8 + 4] = b.x; Xs[s][3 + u * 8 + 5] = b.y;
        Xs[s][3 + u * 8 + 6] = b.z; Xs[s][3 + u * 8 + 7] = b.w;
        if (u == 0) {
            Xs[s][0] = xyz[3 * id + 0] - cs[0];
            Xs[s][1] = xyz[3 * id + 1] - cs[1];
            Xs[s][2] = xyz[3 * id + 2] - cs[2];
        }
    }
    __syncthreads();

    // layer 1: each thread computes 8 of 64 outputs for its sample
    {
        float acc[8];
        #pragma unroll
        for (int v = 0; v < 8; ++v) acc[v] = b1s[u * 8 + v];
        for (int k = 0; k < D0; ++k) {
            float xk = Xs[s][k];
            float4 wa = *(const float4*)&W1s[k * H1DIM + u * 8 + 0];
            float4 wb = *(const float4*)&W1s[k * H1DIM + u * 8 + 4];
            acc[0] = fmaf(xk, wa.x, acc[0]); acc[1] = fmaf(xk, wa.y, acc[1]);
            acc[2] = fmaf(xk, wa.z, acc[2]); acc[3] = fmaf(xk, wa.w, acc[3]);
            acc[4] = fmaf(xk, wb.x, acc[4]); acc[5] = fmaf(xk, wb.y, acc[5]);
            acc[6] = fmaf(xk, wb.z, acc[6]); acc[7] = fmaf(xk, wb.w, acc[7]);
        }
        #pragma unroll
        for (int v = 0; v < 8; ++v) {
            float a = acc[v];
            H1s[s][u * 8 + v] = 0.5f * a * (1.0f + erff(a * 0.70710678118654752f));
        }
    }
    __syncthreads();

    // layer 2: each thread computes 16 of 128 outputs for its sample
    {
        float acc[16];
        #pragma unroll
        for (int v = 0; v < 16; ++v) acc[v] = b2s[u * 16 + v];
        for (int k = 0; k < H1DIM; ++k) {
            float hk = H1s[s][k];
            #pragma unroll
            for (int q = 0; q < 4; ++q) {
                float4 w = *(const float4*)&W2s[k * H2DIM + u * 16 + q * 4];
                acc[q * 4 + 0] = fmaf(hk, w.x, acc[q * 4 + 0]);
                acc[q * 4 + 1] = fmaf(hk, w.y, acc[q * 4 + 1]);
                acc[q * 4 + 2] = fmaf(hk, w.z, acc[q * 4 + 2]);
                acc[q * 4 + 3] = fmaf(hk, w.w, acc[q * 4 + 3]);
            }
        }
        #pragma unroll
        for (int v = 0; v < 16; ++v) {
            float a = acc[v];
            H2s[s][u * 16 + v] = 0.5f * a * (1.0f + erff(a * 0.70710678118654752f));
        }
    }
    __syncthreads();

    // maxpool over 32 samples
    if (t < H2DIM) {
        float mx = H2s[0][t];
        #pragma unroll 4
        for (int ss = 1; ss < NSAMPLE; ++ss) mx = fmaxf(mx, H2s[ss][t]);
        out_pooled[(size_t)m * H2DIM + t] = mx;
    }
}

// ---------------------------------------------------------------------------
extern "C" void kernel_launch(void* const* d_in, const int* in_sizes, int n_in,
                              void* d_out, int out_size, void* d_ws, size_t ws_size,
                              hipStream_t stream) {
    const float* xyz  = (const float*)d_in[0];
    const float* feat = (const float*)d_in[1];
    const float* W1   = (const float*)d_in[2];
    const float* b1   = (const float*)d_in[3];
    const float* W2   = (const float*)d_in[4];
    const float* b2   = (const float*)d_in[5];
    float* out = (float*)d_out;
    int*   gidx = (int*)d_ws;   // 2048*32 ints = 256 KiB scratch

    fps_kernel<<<1, FT, 0, stream>>>(xyz, out);
    ballq_kernel<<<NPOINT, BT, 0, stream>>>(xyz, out, gidx);
    mlp_kernel<<<NPOINT, 256, 0, stream>>>(xyz, feat, W1, b1, W2, b2,
                                           out, gidx, out + 3 * NPOINT);
}

// Round 4
// 6078.498 us; speedup vs baseline: 2.1699x; 1.0005x over previous
//
#include <hip/hip_runtime.h>
#include <math.h>

#define NPTS    32768
#define NPOINT  2048
#define NSAMPLE 32
#define RADIUS2 0.25f
#define D_IN    64
#define D0      67
#define H1DIM   64
#define H2DIM   128

// ---------------------------------------------------------------------------
// Kernel A: farthest point sampling (single block, bit-exact vs numpy fp32)
// 512 thr x 64 pts. NOTE: the 2nd __launch_bounds__ arg behaves as MIN BLOCKS
// PER CU on this toolchain (R2: arg absent -> 128 regs; R3: arg=2 -> 128 regs,
// spill). arg=1 -> 8 waves/CU -> 2 waves/SIMD -> 256-VGPR cap: X,Y,D (192) fit
// in registers with headroom. LDS (128 KiB) already limits to 1 block/CU, so
// occupancy is unchanged. z in LDS laid out so each wave ds_read_b128 is
// lane-consecutive (conflict-free, verified 0 conflicts in R3).
// Deferred argmax: per-point cost is min+max only; winning index recovered by
// equality scan on winner threads + LDS atomicMin (first-occurrence exact).
// Point ownership: thread t owns p = g*2048 + 4t + k (g=0..15, k=0..3).
// ---------------------------------------------------------------------------
#define FT 512
#define FK 64   // points per thread; FT*FK == NPTS

__global__ __launch_bounds__(FT, 1) void fps_kernel(const float* __restrict__ xyz,
                                                    float* __restrict__ d_out)
{
#pragma clang fp contract(off)
    __shared__ float Zs[NPTS];          // 128 KiB, Zs[p] = z of point p
    __shared__ float red_v[FT / 64];    // 8 wave partials
    __shared__ int   widx_s[2];         // ping-pong argmax index slot

    const int t = threadIdx.x;

    float X[FK], Y[FK], D[FK];

    #pragma unroll
    for (int g = 0; g < 16; ++g)
        #pragma unroll
        for (int k = 0; k < 4; ++k) {
            const int j = g * 4 + k;
            const int p = g * 2048 + t * 4 + k;
            X[j] = xyz[3 * p + 0];
            Y[j] = xyz[3 * p + 1];
            Zs[p] = xyz[3 * p + 2];
            D[j] = 1e38f;
        }
    if (t == 0) { widx_s[0] = 0x7fffffff; widx_s[1] = 0x7fffffff; }
    float fx = xyz[0], fy = xyz[1], fz = xyz[2];   // far = 0 at start
    __syncthreads();

    for (int i = 0; i < NPOINT; ++i) {
        const int par = i & 1;
        if (t == 0) {   // emit current far point's coords as new_xyz[i]
            d_out[3 * i + 0] = fx;
            d_out[3 * i + 1] = fy;
            d_out[3 * i + 2] = fz;
        }

        // --- distance update + max (4 independent accumulators for ILP) ---
        float m0 = -1.0f, m1 = -1.0f, m2 = -1.0f, m3 = -1.0f;
        #pragma unroll
        for (int g = 0; g < 16; ++g) {
            float4 z4 = *(const float4*)&Zs[g * 2048 + t * 4];  // lane-consecutive
            {   const int j = g * 4 + 0;
                float dx = X[j] - fx, dy = Y[j] - fy, dz = z4.x - fz;
                float d = ((dx * dx) + (dy * dy)) + (dz * dz);
                float Dn = fminf(D[j], d); D[j] = Dn; m0 = fmaxf(m0, Dn); }
            {   const int j = g * 4 + 1;
                float dx = X[j] - fx, dy = Y[j] - fy, dz = z4.y - fz;
                float d = ((dx * dx) + (dy * dy)) + (dz * dz);
                float Dn = fminf(D[j], d); D[j] = Dn; m1 = fmaxf(m1, Dn); }
            {   const int j = g * 4 + 2;
                float dx = X[j] - fx, dy = Y[j] - fy, dz = z4.z - fz;
                float d = ((dx * dx) + (dy * dy)) + (dz * dz);
                float Dn = fminf(D[j], d); D[j] = Dn; m2 = fmaxf(m2, Dn); }
            {   const int j = g * 4 + 3;
                float dx = X[j] - fx, dy = Y[j] - fy, dz = z4.w - fz;
                float d = ((dx * dx) + (dy * dy)) + (dz * dz);
                float Dn = fminf(D[j], d); D[j] = Dn; m3 = fmaxf(m3, Dn); }
        }
        const float tmax = fmaxf(fmaxf(m0, m1), fmaxf(m2, m3));  // thread max

        // --- wave max ---
        float wmax = tmax;
        #pragma unroll
        for (int mask = 32; mask >= 1; mask >>= 1)
            wmax = fmaxf(wmax, __shfl_xor(wmax, mask, 64));
        if ((t & 63) == 0) red_v[t >> 6] = wmax;
        __syncthreads();                                   // A

        // --- every wave redundantly reduces the 8 partials -> gmax ---
        float pv = red_v[t & 7];
        #pragma unroll
        for (int mask = 4; mask >= 1; mask >>= 1)
            pv = fmaxf(pv, __shfl_xor(pv, mask, 8));
        const float gmax = pv;

        // --- winning thread(s) recover first (lowest) index by equality ---
        if (tmax == gmax) {
            int loc = -1;
            #pragma unroll
            for (int j = FK - 1; j >= 0; --j)
                if (D[j] == gmax) loc = j;    // downward scan -> lowest j wins
            if (loc >= 0)
                atomicMin(&widx_s[par], (loc >> 2) * 2048 + t * 4 + (loc & 3));
        }
        __syncthreads();                                   // C

        const int w = __builtin_amdgcn_readfirstlane(widx_s[par]);
        if (t == 0) widx_s[par ^ 1] = 0x7fffffff;
        // slot par^1: last read was before barrier A (iter i-1 epoch);
        // next atomicMin is after barrier A of iter i+1 -> race-free.
        fx = xyz[3 * w + 0];   // uniform address -> scalar load broadcast
        fy = xyz[3 * w + 1];
        fz = xyz[3 * w + 2];
    }
}

// ---------------------------------------------------------------------------
// Kernel B: ball query — exact (d2, idx)-lexicographic 32-smallest per centroid
// ---------------------------------------------------------------------------
#define BT   256
#define BCAP 3072   // in-radius cap (expected worst ~1100 near origin)

__global__ __launch_bounds__(BT) void ballq_kernel(const float* __restrict__ xyz,
                                                   const float* __restrict__ newxyz,
                                                   int* __restrict__ gidx)
{
#pragma clang fp contract(off)
    __shared__ float Ld[BCAP + 128];
    __shared__ int   Li[BCAP + 128];
    __shared__ int   cnt, pcnt;
    __shared__ float cs[3];
    __shared__ float rv[BT / 64];
    __shared__ int   ri[BT / 64], rj[BT / 64];

    const int m = blockIdx.x;
    const int t = threadIdx.x;

    if (t == 0) {
        cnt = 0; pcnt = 0;
        cs[0] = newxyz[3 * m + 0];
        cs[1] = newxyz[3 * m + 1];
        cs[2] = newxyz[3 * m + 2];
    }
    __syncthreads();
    const float cx = cs[0], cy = cs[1], cz = cs[2];

    for (int p = t; p < NPTS; p += BT) {
        float dx = cx - xyz[3 * p + 0];
        float dy = cy - xyz[3 * p + 1];
        float dz = cz - xyz[3 * p + 2];
        float d2 = ((dx * dx) + (dy * dy)) + (dz * dz);
        if (!(d2 > RADIUS2)) {                    // in radius (keeps d2 == r^2)
            int pos = atomicAdd(&cnt, 1);
            if (pos < BCAP) { Ld[pos] = d2; Li[pos] = p; }
        } else if (p < 128) {                     // padding candidates (masked 1e9)
            int pos = atomicAdd(&pcnt, 1);
            Ld[BCAP + pos] = 1e9f;
            Li[BCAP + pos] = p;
        }
    }
    __syncthreads();

    const int L = (cnt < BCAP) ? cnt : BCAP;
    const int P = pcnt;
    if (t < P) {  // compact pads to follow the in-radius list
        float d = Ld[BCAP + t];
        int   x = Li[BCAP + t];
        Ld[L + t] = d;
        Li[L + t] = x;
    }
    __syncthreads();
    const int M = L + P;

    for (int r = 0; r < NSAMPLE; ++r) {
        float bd = 3e38f;
        int   bi = 0x7fffffff;
        int   bj = 0;
        for (int j = t; j < M; j += BT) {
            float d = Ld[j];
            int   x = Li[j];
            if (d < bd || (d == bd && x < bi)) { bd = d; bi = x; bj = j; }
        }
        #pragma unroll
        for (int mask = 32; mask >= 1; mask >>= 1) {
            float ov = __shfl_xor(bd, mask, 64);
            int   oi = __shfl_xor(bi, mask, 64);
            int   oj = __shfl_xor(bj, mask, 64);
            if (ov < bd || (ov == bd && oi < bi)) { bd = ov; bi = oi; bj = oj; }
        }
        if ((t & 63) == 0) { rv[t >> 6] = bd; ri[t >> 6] = bi; rj[t >> 6] = bj; }
        __syncthreads();
        if (t == 0) {
            float v0 = rv[0]; int i0 = ri[0]; int j0 = rj[0];
            for (int w = 1; w < BT / 64; ++w) {
                if (rv[w] < v0 || (rv[w] == v0 && ri[w] < i0)) { v0 = rv[w]; i0 = ri[w]; j0 = rj[w]; }
            }
            gidx[m * NSAMPLE + r] = i0;
            Ld[j0] = 3e38f;   // remove from candidate set
        }
        __syncthreads();
    }
}

// ---------------------------------------------------------------------------
// Kernel C: gather -> MLP(67->64->128, exact GELU) -> maxpool, 1 block/centroid
// ---------------------------------------------------------------------------
__global__ __launch_bounds__(256) void mlp_kernel(const float* __restrict__ xyz,
                                                  const float* __restrict__ feat,
                                                  const float* __restrict__ W1,
                                                  const float* __restrict__ b1,
                                                  const float* __restrict__ W2,
                                                  const float* __restrict__ b2,
                                                  const float* __restrict__ newxyz,
                                                  const int* __restrict__ gidx,
                                                  float* __restrict__ out_pooled)
{
    __shared__ float W1s[D0 * H1DIM];            // 17152 B
    __shared__ float W2s[H1DIM * H2DIM];         // 32768 B
    __shared__ float b1s[H1DIM];
    __shared__ float b2s[H2DIM];
    __shared__ float Xs[NSAMPLE][D0 + 1];        // 68 stride
    __shared__ float H1s[NSAMPLE][H1DIM + 4];    // 68 stride
    __shared__ float H2s[NSAMPLE][H2DIM + 4];    // 132 stride
    __shared__ int   idxs[NSAMPLE];
    __shared__ float cs[3];

    const int m = blockIdx.x;
    const int t = threadIdx.x;

    for (int i = t; i < D0 * H1DIM; i += 256) W1s[i] = W1[i];
    for (int i = t; i < H1DIM * H2DIM; i += 256) W2s[i] = W2[i];
    if (t < H1DIM) b1s[t] = b1[t];
    if (t < H2DIM) b2s[t] = b2[t];
    if (t < NSAMPLE) idxs[t] = gidx[m * NSAMPLE + t];
    if (t < 3) cs[t] = newxyz[3 * m + t];
    __syncthreads();

    const int s  = t >> 3;   // sample 0..31
    const int u  = t & 7;    // sub-worker 0..7

    {   // gather: g_xyz (relative) + feat
        const int id = idxs[s];
        const float4* f4 = (const float4*)(feat + (size_t)id * D_IN);
        float4 a = f4[u * 2 + 0];
        float4 b = f4[u * 2 + 1];
        Xs[s][3 + u * 8 + 0] = a.x; Xs[s][3 + u * 8 + 1] = a.y;
        Xs[s][3 + u * 8 + 2] = a.z; Xs[s][3 + u * 8 + 3] = a.w;
        Xs[s][3 + u * 8 + 4] = b.x; Xs[s][3 + u * 8 + 5] = b.y;
        Xs[s][3 + u * 8 + 6] = b.z; Xs[s][3 + u * 8 + 7] = b.w;
        if (u == 0) {
            Xs[s][0] = xyz[3 * id + 0] - cs[0];
            Xs[s][1] = xyz[3 * id + 1] - cs[1];
            Xs[s][2] = xyz[3 * id + 2] - cs[2];
        }
    }
    __syncthreads();

    // layer 1: each thread computes 8 of 64 outputs for its sample
    {
        float acc[8];
        #pragma unroll
        for (int v = 0; v < 8; ++v) acc[v] = b1s[u * 8 + v];
        for (int k = 0; k < D0; ++k) {
            float xk = Xs[s][k];
            float4 wa = *(const float4*)&W1s[k * H1DIM + u * 8 + 0];
            float4 wb = *(const float4*)&W1s[k * H1DIM + u * 8 + 4];
            acc[0] = fmaf(xk, wa.x, acc[0]); acc[1] = fmaf(xk, wa.y, acc[1]);
            acc[2] = fmaf(xk, wa.z, acc[2]); acc[3] = fmaf(xk, wa.w, acc[3]);
            acc[4] = fmaf(xk, wb.x, acc[4]); acc[5] = fmaf(xk, wb.y, acc[5]);
            acc[6] = fmaf(xk, wb.z, acc[6]); acc[7] = fmaf(xk, wb.w, acc[7]);
        }
        #pragma unroll
        for (int v = 0; v < 8; ++v) {
            float a = acc[v];
            H1s[s][u * 8 + v] = 0.5f * a * (1.0f + erff(a * 0.70710678118654752f));
        }
    }
    __syncthreads();

    // layer 2: each thread computes 16 of 128 outputs for its sample
    {
        float acc[16];
        #pragma unroll
        for (int v = 0; v < 16; ++v) acc[v] = b2s[u * 16 + v];
        for (int k = 0; k < H1DIM; ++k) {
            float hk = H1s[s][k];
            #pragma unroll
            for (int q = 0; q < 4; ++q) {
                float4 w = *(const float4*)&W2s[k * H2DIM + u * 16 + q * 4];
                acc[q * 4 + 0] = fmaf(hk, w.x, acc[q * 4 + 0]);
                acc[q * 4 + 1] = fmaf(hk, w.y, acc[q * 4 + 1]);
                acc[q * 4 + 2] = fmaf(hk, w.z, acc[q * 4 + 2]);
                acc[q * 4 + 3] = fmaf(hk, w.w, acc[q * 4 + 3]);
            }
        }
        #pragma unroll
        for (int v = 0; v < 16; ++v) {
            float a = acc[v];
            H2s[s][u * 16 + v] = 0.5f * a * (1.0f + erff(a * 0.70710678118654752f));
        }
    }
    __syncthreads();

    // maxpool over 32 samples
    if (t < H2DIM) {
        float mx = H2s[0][t];
        #pragma unroll 4
        for (int ss = 1; ss < NSAMPLE; ++ss) mx = fmaxf(mx, H2s[ss][t]);
        out_pooled[(size_t)m * H2DIM + t] = mx;
    }
}

// ---------------------------------------------------------------------------
extern "C" void kernel_launch(void* const* d_in, const int* in_sizes, int n_in,
                              void* d_out, int out_size, void* d_ws, size_t ws_size,
                              hipStream_t stream) {
    const float* xyz  = (const float*)d_in[0];
    const float* feat = (const float*)d_in[1];
    const float* W1   = (const float*)d_in[2];
    const float* b1   = (const float*)d_in[3];
    const float* W2   = (const float*)d_in[4];
    const float* b2   = (const float*)d_in[5];
    float* out = (float*)d_out;
    int*   gidx = (int*)d_ws;   // 2048*32 ints = 256 KiB scratch

    fps_kernel<<<1, FT, 0, stream>>>(xyz, out);
    ballq_kernel<<<NPOINT, BT, 0, stream>>>(xyz, out, gidx);
    mlp_kernel<<<NPOINT, 256, 0, stream>>>(xyz, feat, W1, b1, W2, b2,
                                           out, gidx, out + 3 * NPOINT);
}